// Round 7
// baseline (3800.308 us; speedup 1.0000x reference)
//
#include <hip/hip_runtime.h>

#define B_    64
#define T_    512
#define D_    512
#define KF    1024      // fused weight K = [h(512) ; x(512)]
#define NGRP  4         // batch groups
#define NSLC  16        // WG slices per group
#define GB    16        // batches per group

using short8 = __attribute__((ext_vector_type(8))) short;
using f32x4  = __attribute__((ext_vector_type(4))) float;

__device__ __forceinline__ unsigned short f2bf(float f) {
    unsigned int u = __float_as_uint(f);
    u = (u + 0x7fffu + ((u >> 16) & 1u)) >> 16;
    return (unsigned short)u;
}
__device__ __forceinline__ float sigmf(float x)  { return 1.0f / (1.0f + __expf(-x)); }
__device__ __forceinline__ float tanh_f(float x) { return 1.0f - 2.0f / (1.0f + __expf(2.0f * x)); }

// LDS tile layout: [16 rows][1024 B]; XOR spreads both the 32B-stride staging
// writes (via kb>>7) and the row-wise MFMA reads (via row&7) across banks.
__device__ __forceinline__ int loff(int row, int kb) {
    return row * 1024 + (kb ^ ((((row & 7) ^ ((kb >> 7) & 7)) << 4)));
}
__device__ __forceinline__ bool fresh2(unsigned long long w, unsigned want) {
    return (((unsigned)w & 0xffffu) == want) & (((unsigned)(w >> 32) & 0xffffu) == want);
}
__device__ __forceinline__ unsigned pk(unsigned long long w) {   // 2 payloads -> 1 uint
    return (unsigned)((w >> 16) & 0xffffu) | ((unsigned)(w >> 32) & 0xffff0000u);
}

// ---- prep: X fp32 -> bf16 ----
__global__ void prep_x(const float* __restrict__ X, unsigned short* __restrict__ Xb, int n4) {
    int stride = gridDim.x * blockDim.x;
    for (int i = blockIdx.x * blockDim.x + threadIdx.x; i < n4; i += stride) {
        float4 v = ((const float4*)X)[i];
        ushort4 o;
        o.x = f2bf(v.x); o.y = f2bf(v.y); o.z = f2bf(v.z); o.w = f2bf(v.w);
        ((ushort4*)Xb)[i] = o;
    }
}

// ---- prep: fused weight Wcat[r = o*4+g][k]; gate g: 0=i(Ui,Wi) 1=f(Uf,Wi quirk) 2=c(Uc,Wc) 3=o(Uo,Wo)
__global__ void prep_w(const float* __restrict__ Wi, const float* __restrict__ Wc,
                       const float* __restrict__ Wo,
                       const float* __restrict__ Ui, const float* __restrict__ Uf,
                       const float* __restrict__ Uc, const float* __restrict__ Uo,
                       unsigned short* __restrict__ Wcat) {
    int idx = blockIdx.x * blockDim.x + threadIdx.x;
    if (idx >= 2048 * 1024) return;
    int r = idx >> 10, k = idx & 1023;
    int o = r >> 2, g = r & 3;
    const float* U = (g == 0) ? Ui : (g == 1) ? Uf : (g == 2) ? Uc : Uo;
    const float* W = (g < 2) ? Wi : (g == 2) ? Wc : Wo;
    float v = (k < 512) ? U[o * 512 + k] : W[o * 512 + (k - 512)];
    Wcat[idx] = f2bf(v);
}

// ---- persistent recurrence, 64 WGs (1/CU, 8 waves = 2/SIMD) ----
// WG (g: 16 batches, s: 128 gate-rows = 32 ocols); wave owns 16 rows x full K.
// h exchange: self-validating tagged 4B words -> no flags, no drains.
__launch_bounds__(512, 2)
__global__ void lstm_rec(const unsigned short* __restrict__ Xb,
                         const unsigned short* __restrict__ Wcat,
                         unsigned int* __restrict__ hbuf,     // [2][64][512] tagged words
                         float* __restrict__ out,             // H then C (fp32)
                         const float* __restrict__ bi, const float* __restrict__ bc,
                         const float* __restrict__ bo, const float* __restrict__ bUf,
                         const float* __restrict__ bUc, const float* __restrict__ bUo) {
    __shared__ __align__(16) unsigned char Hl[2][16 * 1024];   // h_{t-1} bf16 tiles (parity)
    __shared__ __align__(16) unsigned char Xl[2][16 * 1024];   // x_{t+1} bf16 tiles (parity)

    const int tid  = threadIdx.x;
    const int bid  = blockIdx.x;
    const int g    = bid >> 4;
    const int s    = bid & 15;
    const int wave = tid >> 6;
    const int lane = tid & 63;
    const int q    = lane >> 4;
    const int bl   = lane & 15;

    // ---- resident fused weights: 32 x short8 (atomic loads -> stay in unified VGPR/AGPR) ----
    const unsigned short* wrow = Wcat + (size_t)(s * 128 + wave * 16 + bl) * KF + q * 8;
    short8 Uh[16], Ux[16];
    #pragma unroll
    for (int kt = 0; kt < 16; ++kt) {
        union { unsigned long long u[2]; short8 v; } wh, wx;
        const unsigned long long* ph = (const unsigned long long*)(wrow + kt * 32);
        const unsigned long long* px = (const unsigned long long*)(wrow + 512 + kt * 32);
        wh.u[0] = __hip_atomic_load(ph,     __ATOMIC_RELAXED, __HIP_MEMORY_SCOPE_AGENT);
        wh.u[1] = __hip_atomic_load(ph + 1, __ATOMIC_RELAXED, __HIP_MEMORY_SCOPE_AGENT);
        wx.u[0] = __hip_atomic_load(px,     __ATOMIC_RELAXED, __HIP_MEMORY_SCOPE_AGENT);
        wx.u[1] = __hip_atomic_load(px + 1, __ATOMIC_RELAXED, __HIP_MEMORY_SCOPE_AGENT);
        Uh[kt] = wh.v;
        Ux[kt] = wx.v;
    }

    // ---- per-lane gate identity: ocol og, batch g*16+bl ----
    const int og = s * 32 + wave * 4 + q;
    const float bi0 = bi[og],           bf0 = bi[og] + bUf[og];
    const float bc0 = bc[og] + bUc[og], bo0 = bo[og] + bUo[og];
    float cst = 0.f;

    // ---- staging identity: thread (sb=batch row, seg=16-col chunk) ----
    const int sb  = tid >> 5;
    const int seg = tid & 31;
    const unsigned short* xst = Xb + (size_t)(g * GB + sb) * T_ * D_ + seg * 16;
    const unsigned short* xbl = Xb + (size_t)(g * GB + bl) * T_ * D_ + q * 8;

    float* Hout = out;
    float* Cout = out + (size_t)B_ * T_ * D_;

    // ---- prologue: xa for t=0 direct from global; prefetch x_1 ----
    f32x4 xa0 = {0.f, 0.f, 0.f, 0.f}, xa1 = {0.f, 0.f, 0.f, 0.f};
    #pragma unroll
    for (int kt = 0; kt < 16; kt += 2) {
        short8 b0 = *(const short8*)(xbl + kt * 32);
        short8 b1 = *(const short8*)(xbl + (kt + 1) * 32);
        xa0 = __builtin_amdgcn_mfma_f32_16x16x32_bf16(Ux[kt],     b0, xa0, 0, 0, 0);
        xa1 = __builtin_amdgcn_mfma_f32_16x16x32_bf16(Ux[kt + 1], b1, xa1, 0, 0, 0);
    }
    uint4 xc0, xc1;
    {
        const uint4* xs = (const uint4*)(xst + (size_t)1 * D_);
        xc0 = xs[0]; xc1 = xs[1];
    }

    for (int t = 0; t < T_; ++t) {
        const int cur = t & 1;
        const bool hasNext = (t + 1 < T_);

        // ---- prefetch x_{t+2} (in flight across the whole step; survives raw barrier) ----
        uint4 xn0v = xc0, xn1v = xc1;
        if (t + 2 < T_) {
            const uint4* xs = (const uint4*)(xst + (size_t)(t + 2) * D_);
            xn0v = xs[0]; xn1v = xs[1];
        }

        // ---- poll + stage h_{t-1} -> Hl[cur] (tagged words: data IS the flag) ----
        if (t > 0) {
            const unsigned long long* hw = (const unsigned long long*)
                (hbuf + ((size_t)((t + 1) & 1) * B_ + g * GB + sb) * D_ + seg * 16);
            const unsigned want = (unsigned)t;
            unsigned long long w[8];
            #pragma unroll
            for (int k = 0; k < 8; ++k)
                w[k] = __hip_atomic_load(hw + k, __ATOMIC_RELAXED, __HIP_MEMORY_SCOPE_AGENT);
            bool again;
            do {
                again = false;
                #pragma unroll
                for (int k = 0; k < 8; ++k) {
                    if (!fresh2(w[k], want)) {
                        w[k] = __hip_atomic_load(hw + k, __ATOMIC_RELAXED, __HIP_MEMORY_SCOPE_AGENT);
                        again = true;
                    }
                }
            } while (again);
            *(uint4*)(&Hl[cur][loff(sb, seg * 32)]) =
                make_uint4(pk(w[0]), pk(w[1]), pk(w[2]), pk(w[3]));
            *(uint4*)(&Hl[cur][loff(sb, seg * 32 + 16)]) =
                make_uint4(pk(w[4]), pk(w[5]), pk(w[6]), pk(w[7]));
        }
        // ---- stage x_{t+1} -> Xl[cur^1] ----
        if (hasNext) {
            *(uint4*)(&Xl[cur ^ 1][loff(sb, seg * 32)])      = xc0;
            *(uint4*)(&Xl[cur ^ 1][loff(sb, seg * 32 + 16)]) = xc1;
        }

        // ---- single barrier: LDS-visible only (no vmcnt drain of prefetch/stores) ----
        asm volatile("s_waitcnt lgkmcnt(0)" ::: "memory");
        __builtin_amdgcn_s_barrier();

        // ---- h-MFMA (step t) ----
        f32x4 ha0 = {0.f, 0.f, 0.f, 0.f}, ha1 = {0.f, 0.f, 0.f, 0.f};
        if (t > 0) {
            #pragma unroll
            for (int kt = 0; kt < 16; kt += 2) {
                short8 a0 = *(const short8*)(&Hl[cur][loff(bl, q * 16 + kt * 64)]);
                short8 a1 = *(const short8*)(&Hl[cur][loff(bl, q * 16 + (kt + 1) * 64)]);
                ha0 = __builtin_amdgcn_mfma_f32_16x16x32_bf16(Uh[kt],     a0, ha0, 0, 0, 0);
                ha1 = __builtin_amdgcn_mfma_f32_16x16x32_bf16(Uh[kt + 1], a1, ha1, 0, 0, 0);
            }
        }
        // ---- x-MFMA (for step t+1) ----
        f32x4 xo0 = {0.f, 0.f, 0.f, 0.f}, xo1 = {0.f, 0.f, 0.f, 0.f};
        if (hasNext) {
            #pragma unroll
            for (int kt = 0; kt < 16; kt += 2) {
                short8 b0 = *(const short8*)(&Xl[cur ^ 1][loff(bl, q * 16 + kt * 64)]);
                short8 b1 = *(const short8*)(&Xl[cur ^ 1][loff(bl, q * 16 + (kt + 1) * 64)]);
                xo0 = __builtin_amdgcn_mfma_f32_16x16x32_bf16(Ux[kt],     b0, xo0, 0, 0, 0);
                xo1 = __builtin_amdgcn_mfma_f32_16x16x32_bf16(Ux[kt + 1], b1, xo1, 0, 0, 0);
            }
        }

        // ---- gates (in-register D-frag: 4 gates of (og, bl)) ----
        f32x4 A = (ha0 + ha1) + (xa0 + xa1);
        float iv = sigmf(A[0] + bi0);
        float fv = sigmf(A[1] + bf0);
        float cc = tanh_f(A[2] + bc0);
        float ov = sigmf(A[3] + bo0);
        float cv = fv * cst + iv * cc;
        float hv = ov * tanh_f(cv);
        cst = cv;
        xa0 = xo0; xa1 = xo1;

        // ---- publish h as tagged word: store is the synchronization ----
        unsigned wrd = ((unsigned)f2bf(hv) << 16) | (unsigned)(t + 1);
        __hip_atomic_store(hbuf + ((size_t)cur * B_ + g * GB + bl) * D_ + og,
                           wrd, __ATOMIC_RELAXED, __HIP_MEMORY_SCOPE_AGENT);

        // ---- streaming outputs (plain stores; L2 merges the 32 ocols per line) ----
        const size_t oi = ((size_t)(g * GB + bl) * T_ + t) * D_ + og;
        Hout[oi] = hv;
        Cout[oi] = cv;

        xc0 = xn0v; xc1 = xn1v;
    }
}

extern "C" void kernel_launch(void* const* d_in, const int* in_sizes, int n_in,
                              void* d_out, int out_size, void* d_ws, size_t ws_size,
                              hipStream_t stream) {
    const float* X   = (const float*)d_in[0];
    const float* Wi  = (const float*)d_in[1];
    const float* bi  = (const float*)d_in[2];
    // d_in[3] = Wf, d_in[4] = bf : unused by reference semantics
    const float* Wc  = (const float*)d_in[5];
    const float* bc  = (const float*)d_in[6];
    const float* Wo  = (const float*)d_in[7];
    const float* bo  = (const float*)d_in[8];
    const float* Ui  = (const float*)d_in[9];
    const float* Uf  = (const float*)d_in[10];
    const float* bUf = (const float*)d_in[11];
    const float* Uc  = (const float*)d_in[12];
    const float* bUc = (const float*)d_in[13];
    const float* Uo  = (const float*)d_in[14];
    const float* bUo = (const float*)d_in[15];

    char* ws = (char*)d_ws;
    const size_t XB_BYTES   = (size_t)B_ * T_ * D_ * 2;   // 33,554,432
    const size_t WCAT_BYTES = (size_t)2048 * 1024 * 2;    //  4,194,304
    const size_t HBUF_BYTES = (size_t)2 * B_ * D_ * 4;    //    262,144 (tagged words)

    unsigned short* Xb   = (unsigned short*)ws;
    unsigned short* Wcat = (unsigned short*)(ws + XB_BYTES);
    unsigned int*   hbuf = (unsigned int*)(ws + XB_BYTES + WCAT_BYTES);

    // zero tags every call (graph replays must start clean)
    hipMemsetAsync(hbuf, 0, HBUF_BYTES, stream);

    prep_x<<<2048, 256, 0, stream>>>(X, Xb, B_ * T_ * D_ / 4);
    prep_w<<<8192, 256, 0, stream>>>(Wi, Wc, Wo, Ui, Uf, Uc, Uo, Wcat);
    lstm_rec<<<NGRP * NSLC, 512, 0, stream>>>(Xb, Wcat, hbuf, (float*)d_out,
                                              bi, bc, bo, bUf, bUc, bUo);
}

// Round 8
// 1726.694 us; speedup vs baseline: 2.2009x; 2.2009x over previous
//
#include <hip/hip_runtime.h>

#define B_    64
#define T_    512
#define D_    512
#define KF    1024      // fused weight K = [h(512) ; x(512)]
#define NGRP  4         // batch groups
#define NSLC  16        // WG slices per group
#define GB    16        // batches per group

using short8 = __attribute__((ext_vector_type(8))) short;
using f32x4  = __attribute__((ext_vector_type(4))) float;

__device__ __forceinline__ unsigned short f2bf(float f) {
    unsigned int u = __float_as_uint(f);
    u = (u + 0x7fffu + ((u >> 16) & 1u)) >> 16;
    return (unsigned short)u;
}
__device__ __forceinline__ float sigmf(float x)  { return 1.0f / (1.0f + __expf(-x)); }
__device__ __forceinline__ float tanh_f(float x) { return 1.0f - 2.0f / (1.0f + __expf(2.0f * x)); }

// LDS tile [16 rows][64 x 16B granules]; XOR spreads the stride-32B staging
// writes AND the row-major MFMA reads across all banks.
__device__ __forceinline__ int loff(int row, int kb) {
    return row * 1024 + (kb ^ ((((row & 7) ^ ((kb >> 7) & 7)) << 4)));
}

// ---- prep: X fp32 -> bf16 ----
__global__ void prep_x(const float* __restrict__ X, unsigned short* __restrict__ Xb, int n4) {
    int stride = gridDim.x * blockDim.x;
    for (int i = blockIdx.x * blockDim.x + threadIdx.x; i < n4; i += stride) {
        float4 v = ((const float4*)X)[i];
        ushort4 o;
        o.x = f2bf(v.x); o.y = f2bf(v.y); o.z = f2bf(v.z); o.w = f2bf(v.w);
        ((ushort4*)Xb)[i] = o;
    }
}

// ---- prep: fused weight Wcat[r = o*4+g][k]; gate g: 0=i(Ui,Wi) 1=f(Uf,Wi quirk) 2=c(Uc,Wc) 3=o(Uo,Wo)
__global__ void prep_w(const float* __restrict__ Wi, const float* __restrict__ Wc,
                       const float* __restrict__ Wo,
                       const float* __restrict__ Ui, const float* __restrict__ Uf,
                       const float* __restrict__ Uc, const float* __restrict__ Uo,
                       unsigned short* __restrict__ Wcat) {
    int idx = blockIdx.x * blockDim.x + threadIdx.x;
    if (idx >= 2048 * 1024) return;
    int r = idx >> 10, k = idx & 1023;
    int o = r >> 2, g = r & 3;
    const float* U = (g == 0) ? Ui : (g == 1) ? Uf : (g == 2) ? Uc : Uo;
    const float* W = (g < 2) ? Wi : (g == 2) ? Wc : Wo;
    float v = (k < 512) ? U[o * 512 + k] : W[o * 512 + (k - 512)];
    Wcat[idx] = f2bf(v);
}

// ---- persistent recurrence, 64 WGs (1/CU, 8 waves = 2/SIMD) ----
// WG (g: 16 batches, s: 128 gate-rows = 32 ocols); wave owns 16 rows x full K resident.
// Cross-WG sync: per-WAVE flag dwords (own-vmcnt drain), 64B line per producer WG.
// One raw s_barrier per step (LDS only); parity double-buffered Hl/Xl.
__launch_bounds__(512, 2)
__global__ void lstm_rec(const unsigned short* __restrict__ Xb,
                         const unsigned short* __restrict__ Wcat,
                         unsigned short* __restrict__ hbuf,   // [2][64][512] bf16
                         unsigned int* __restrict__ hflag,    // [NGRP*NSLC][16] dwords
                         float* __restrict__ out,             // H then C (fp32)
                         const float* __restrict__ bi, const float* __restrict__ bc,
                         const float* __restrict__ bo, const float* __restrict__ bUf,
                         const float* __restrict__ bUc, const float* __restrict__ bUo) {
    __shared__ __align__(16) unsigned char Hl[2][16 * 1024];   // h_{t-1} tiles (parity)
    __shared__ __align__(16) unsigned char Xl[2][16 * 1024];   // x_{t+1} tiles (parity)

    const int tid  = threadIdx.x;
    const int bid  = blockIdx.x;
    const int g    = bid >> 4;
    const int s    = bid & 15;
    const int wave = tid >> 6;
    const int lane = tid & 63;
    const int q    = lane >> 4;
    const int bl   = lane & 15;

    // ---- resident fused weights: 32 x short8 (atomic loads stay in unified VGPR/AGPR file) ----
    const unsigned short* wrow = Wcat + (size_t)(s * 128 + wave * 16 + bl) * KF + q * 8;
    short8 Uh[16], Ux[16];
    #pragma unroll
    for (int kt = 0; kt < 16; ++kt) {
        union { unsigned long long u[2]; short8 v; } wh, wx;
        const unsigned long long* ph = (const unsigned long long*)(wrow + kt * 32);
        const unsigned long long* px = (const unsigned long long*)(wrow + 512 + kt * 32);
        wh.u[0] = __hip_atomic_load(ph,     __ATOMIC_RELAXED, __HIP_MEMORY_SCOPE_AGENT);
        wh.u[1] = __hip_atomic_load(ph + 1, __ATOMIC_RELAXED, __HIP_MEMORY_SCOPE_AGENT);
        wx.u[0] = __hip_atomic_load(px,     __ATOMIC_RELAXED, __HIP_MEMORY_SCOPE_AGENT);
        wx.u[1] = __hip_atomic_load(px + 1, __ATOMIC_RELAXED, __HIP_MEMORY_SCOPE_AGENT);
        Uh[kt] = wh.v;
        Ux[kt] = wx.v;
    }

    // ---- per-lane gate identity: ocol og, batch g*16+bl ----
    const int og = s * 32 + wave * 4 + q;
    const float bi0 = bi[og],           bf0 = bi[og] + bUf[og];
    const float bc0 = bc[og] + bUc[og], bo0 = bo[og] + bUo[og];
    float cst = 0.f;

    // ---- staging identity: thread (sb=batch row, seg=16-col chunk) ----
    const int sb  = tid >> 5;
    const int seg = tid & 31;
    const unsigned short* xst = Xb + (size_t)(g * GB + sb) * T_ * D_ + seg * 16;
    const unsigned short* xbl = Xb + (size_t)(g * GB + bl) * T_ * D_ + q * 8;

    // consumer: the 4 flag dwords of producer WG (seg>>1)'s waves owning my 16 cols
    const unsigned long long* fpoll = (const unsigned long long*)
        (hflag + (size_t)(g * NSLC + (seg >> 1)) * 16 + (seg & 1) * 4);
    // producer: this wave's own flag dword
    unsigned int* myfl = hflag + (size_t)(g * NSLC + s) * 16 + wave;

    float* Hout = out;
    float* Cout = out + (size_t)B_ * T_ * D_;

    // ---- prologue: xa for t=0 direct from global; prefetch x_1 ----
    f32x4 xa0 = {0.f, 0.f, 0.f, 0.f}, xa1 = {0.f, 0.f, 0.f, 0.f};
    #pragma unroll
    for (int kt = 0; kt < 16; kt += 2) {
        short8 b0 = *(const short8*)(xbl + kt * 32);
        short8 b1 = *(const short8*)(xbl + (kt + 1) * 32);
        xa0 = __builtin_amdgcn_mfma_f32_16x16x32_bf16(Ux[kt],     b0, xa0, 0, 0, 0);
        xa1 = __builtin_amdgcn_mfma_f32_16x16x32_bf16(Ux[kt + 1], b1, xa1, 0, 0, 0);
    }
    uint4 xc0, xc1;
    {
        const uint4* xs = (const uint4*)(xst + (size_t)1 * D_);
        xc0 = xs[0]; xc1 = xs[1];
    }

    for (int t = 0; t < T_; ++t) {
        const int cur = t & 1;
        const bool hasNext = (t + 1 < T_);

        // ---- prefetch x_{t+2} (in flight across the raw barrier) ----
        uint4 xn0v = xc0, xn1v = xc1;
        if (t + 2 < T_) {
            const uint4* xs = (const uint4*)(xst + (size_t)(t + 2) * D_);
            xn0v = xs[0]; xn1v = xs[1];
        }

        // ---- poll 4 producer-wave flags, then one-shot gather h_{t-1} ----
        if (t > 0) {
            const unsigned want = (unsigned)t;
            unsigned long long f0, f1;
            do {
                f0 = __hip_atomic_load(fpoll,     __ATOMIC_RELAXED, __HIP_MEMORY_SCOPE_AGENT);
                f1 = __hip_atomic_load(fpoll + 1, __ATOMIC_RELAXED, __HIP_MEMORY_SCOPE_AGENT);
            } while ((unsigned)f0 < want || (unsigned)(f0 >> 32) < want ||
                     (unsigned)f1 < want || (unsigned)(f1 >> 32) < want);
            asm volatile("" ::: "memory");
            const unsigned long long* hs = (const unsigned long long*)
                (hbuf + ((size_t)((t + 1) & 1) * B_ + g * GB + sb) * D_ + seg * 16);
            unsigned long long d0 = __hip_atomic_load(hs + 0, __ATOMIC_RELAXED, __HIP_MEMORY_SCOPE_AGENT);
            unsigned long long d1 = __hip_atomic_load(hs + 1, __ATOMIC_RELAXED, __HIP_MEMORY_SCOPE_AGENT);
            unsigned long long d2 = __hip_atomic_load(hs + 2, __ATOMIC_RELAXED, __HIP_MEMORY_SCOPE_AGENT);
            unsigned long long d3 = __hip_atomic_load(hs + 3, __ATOMIC_RELAXED, __HIP_MEMORY_SCOPE_AGENT);
            *(uint4*)(&Hl[cur][loff(sb, seg * 32)]) =
                make_uint4((unsigned)d0, (unsigned)(d0 >> 32), (unsigned)d1, (unsigned)(d1 >> 32));
            *(uint4*)(&Hl[cur][loff(sb, seg * 32 + 16)]) =
                make_uint4((unsigned)d2, (unsigned)(d2 >> 32), (unsigned)d3, (unsigned)(d3 >> 32));
        }
        // ---- stage x_{t+1} -> Xl[cur^1] ----
        if (hasNext) {
            *(uint4*)(&Xl[cur ^ 1][loff(sb, seg * 32)])      = xc0;
            *(uint4*)(&Xl[cur ^ 1][loff(sb, seg * 32 + 16)]) = xc1;
        }

        // ---- single raw barrier: LDS visibility only ----
        asm volatile("s_waitcnt lgkmcnt(0)" ::: "memory");
        __builtin_amdgcn_s_barrier();

        // ---- h-MFMA (step t), 2 chains ----
        f32x4 ha0 = {0.f, 0.f, 0.f, 0.f}, ha1 = {0.f, 0.f, 0.f, 0.f};
        if (t > 0) {
            #pragma unroll
            for (int kt = 0; kt < 16; kt += 2) {
                short8 a0 = *(const short8*)(&Hl[cur][loff(bl, q * 16 + kt * 64)]);
                short8 a1 = *(const short8*)(&Hl[cur][loff(bl, q * 16 + (kt + 1) * 64)]);
                ha0 = __builtin_amdgcn_mfma_f32_16x16x32_bf16(Uh[kt],     a0, ha0, 0, 0, 0);
                ha1 = __builtin_amdgcn_mfma_f32_16x16x32_bf16(Uh[kt + 1], a1, ha1, 0, 0, 0);
            }
        }

        // ---- gates (in-register D-frag: 4 gates of (og, bl)) ----
        f32x4 A = (ha0 + ha1) + (xa0 + xa1);
        float iv = sigmf(A[0] + bi0);
        float fv = sigmf(A[1] + bf0);
        float cc = tanh_f(A[2] + bc0);
        float ov = sigmf(A[3] + bo0);
        float cv = fv * cst + iv * cc;
        float hv = ov * tanh_f(cv);
        cst = cv;

        // ---- publish h; per-wave drain; per-wave flag ----
        __hip_atomic_store(hbuf + ((size_t)cur * B_ + g * GB + bl) * D_ + og,
                           f2bf(hv), __ATOMIC_RELAXED, __HIP_MEMORY_SCOPE_AGENT);
        asm volatile("s_waitcnt vmcnt(0)" ::: "memory");
        if (lane == 0)
            __hip_atomic_store(myfl, (unsigned)(t + 1), __ATOMIC_RELAXED, __HIP_MEMORY_SCOPE_AGENT);

        // ---- streaming outputs (off the flag path) ----
        const size_t oi = ((size_t)(g * GB + bl) * T_ + t) * D_ + og;
        Hout[oi] = hv;
        Cout[oi] = cv;

        // ---- x-MFMA for t+1 (off critical path) ----
        if (hasNext) {
            f32x4 xo0 = {0.f, 0.f, 0.f, 0.f}, xo1 = {0.f, 0.f, 0.f, 0.f};
            #pragma unroll
            for (int kt = 0; kt < 16; kt += 2) {
                short8 b0 = *(const short8*)(&Xl[cur ^ 1][loff(bl, q * 16 + kt * 64)]);
                short8 b1 = *(const short8*)(&Xl[cur ^ 1][loff(bl, q * 16 + (kt + 1) * 64)]);
                xo0 = __builtin_amdgcn_mfma_f32_16x16x32_bf16(Ux[kt],     b0, xo0, 0, 0, 0);
                xo1 = __builtin_amdgcn_mfma_f32_16x16x32_bf16(Ux[kt + 1], b1, xo1, 0, 0, 0);
            }
            xa0 = xo0; xa1 = xo1;
        }

        xc0 = xn0v; xc1 = xn1v;
    }
}

extern "C" void kernel_launch(void* const* d_in, const int* in_sizes, int n_in,
                              void* d_out, int out_size, void* d_ws, size_t ws_size,
                              hipStream_t stream) {
    const float* X   = (const float*)d_in[0];
    const float* Wi  = (const float*)d_in[1];
    const float* bi  = (const float*)d_in[2];
    // d_in[3] = Wf, d_in[4] = bf : unused by reference semantics
    const float* Wc  = (const float*)d_in[5];
    const float* bc  = (const float*)d_in[6];
    const float* Wo  = (const float*)d_in[7];
    const float* bo  = (const float*)d_in[8];
    const float* Ui  = (const float*)d_in[9];
    const float* Uf  = (const float*)d_in[10];
    const float* bUf = (const float*)d_in[11];
    const float* Uc  = (const float*)d_in[12];
    const float* bUc = (const float*)d_in[13];
    const float* Uo  = (const float*)d_in[14];
    const float* bUo = (const float*)d_in[15];

    char* ws = (char*)d_ws;
    const size_t XB_BYTES   = (size_t)B_ * T_ * D_ * 2;     // 33,554,432
    const size_t WCAT_BYTES = (size_t)2048 * 1024 * 2;      //  4,194,304
    const size_t HBUF_BYTES = (size_t)2 * B_ * D_ * 2;      //    131,072 (bf16)
    const size_t FLAG_BYTES = (size_t)NGRP * NSLC * 16 * 4; //      4,096

    unsigned short* Xb    = (unsigned short*)ws;
    unsigned short* Wcat  = (unsigned short*)(ws + XB_BYTES);
    unsigned short* hbuf  = (unsigned short*)(ws + XB_BYTES + WCAT_BYTES);
    unsigned int*   hflag = (unsigned int*)(ws + XB_BYTES + WCAT_BYTES + HBUF_BYTES);

    // zero h and per-wave flags every call (graph replays must start clean)
    hipMemsetAsync(hbuf, 0, HBUF_BYTES + FLAG_BYTES, stream);

    prep_x<<<2048, 256, 0, stream>>>(X, Xb, B_ * T_ * D_ / 4);
    prep_w<<<8192, 256, 0, stream>>>(Wi, Wc, Wo, Ui, Uf, Uc, Uo, Wcat);
    lstm_rec<<<NGRP * NSLC, 512, 0, stream>>>(Xb, Wcat, hbuf, hflag, (float*)d_out,
                                              bi, bc, bo, bUf, bUc, bUo);
}

// Round 10
// 1470.818 us; speedup vs baseline: 2.5838x; 1.1740x over previous
//
#include <hip/hip_runtime.h>

#define B_    64
#define T_    512
#define D_    512
#define KF    1024      // fused weight K = [h(512) ; x(512)]
#define NGRP  4         // batch groups
#define NSLC  16        // WG slices per group
#define GB    16        // batches per group

using short8 = __attribute__((ext_vector_type(8))) short;
using f32x4  = __attribute__((ext_vector_type(4))) float;

__device__ __forceinline__ unsigned short f2bf(float f) {
    unsigned int u = __float_as_uint(f);
    u = (u + 0x7fffu + ((u >> 16) & 1u)) >> 16;
    return (unsigned short)u;
}
__device__ __forceinline__ float sigmf(float x)  { return 1.0f / (1.0f + __expf(-x)); }
__device__ __forceinline__ float tanh_f(float x) { return 1.0f - 2.0f / (1.0f + __expf(2.0f * x)); }

// LDS tile [16 rows][1024 B]; XOR spreads stride-32B staging writes (~4-way)
// and row-major MFMA reads across banks. Bijective per row. (Proven in R8.)
__device__ __forceinline__ int loff(int row, int kb) {
    return row * 1024 + (kb ^ ((((row & 7) ^ ((kb >> 7) & 7)) << 4)));
}

// ---- prep: X fp32 -> bf16 ----
__global__ void prep_x(const float* __restrict__ X, unsigned short* __restrict__ Xb, int n4) {
    int stride = gridDim.x * blockDim.x;
    for (int i = blockIdx.x * blockDim.x + threadIdx.x; i < n4; i += stride) {
        float4 v = ((const float4*)X)[i];
        ushort4 o;
        o.x = f2bf(v.x); o.y = f2bf(v.y); o.z = f2bf(v.z); o.w = f2bf(v.w);
        ((ushort4*)Xb)[i] = o;
    }
}

// ---- prep: fused weight Wcat[r = o*4+g][k]; gate g: 0=i(Ui,Wi) 1=f(Uf,Wi quirk) 2=c(Uc,Wc) 3=o(Uo,Wo)
__global__ void prep_w(const float* __restrict__ Wi, const float* __restrict__ Wc,
                       const float* __restrict__ Wo,
                       const float* __restrict__ Ui, const float* __restrict__ Uf,
                       const float* __restrict__ Uc, const float* __restrict__ Uo,
                       unsigned short* __restrict__ Wcat) {
    int idx = blockIdx.x * blockDim.x + threadIdx.x;
    if (idx >= 2048 * 1024) return;
    int r = idx >> 10, k = idx & 1023;
    int o = r >> 2, g = r & 3;
    const float* U = (g == 0) ? Ui : (g == 1) ? Uf : (g == 2) ? Uc : Uo;
    const float* W = (g < 2) ? Wi : (g == 2) ? Wc : Wo;
    float v = (k < 512) ? U[o * 512 + k] : W[o * 512 + (k - 512)];
    Wcat[idx] = f2bf(v);
}

// ---- persistent recurrence, 64 WGs (1/CU, 8 waves = EXACTLY 2/SIMD) ----
// Proven R6 skeleton: per-producer padded flags, per-thread direct poll,
// single-buffered Hl/Xl, __syncthreads b2 before flag. Deltas: loff swizzle
// (R8-proven) + raw lgkm-only b1 (R7/R8-proven).
__attribute__((amdgpu_waves_per_eu(2, 2)))
__launch_bounds__(512)
__global__ void lstm_rec(const unsigned short* __restrict__ Xb,
                         const unsigned short* __restrict__ Wcat,
                         unsigned short* __restrict__ hbuf,   // [2][64][512] bf16
                         unsigned int* __restrict__ hflag,    // [NGRP*NSLC] padded x16 dwords
                         float* __restrict__ out,             // H then C (fp32)
                         const float* __restrict__ bi, const float* __restrict__ bc,
                         const float* __restrict__ bo, const float* __restrict__ bUf,
                         const float* __restrict__ bUc, const float* __restrict__ bUo) {
    __shared__ __align__(16) unsigned char Hl[16 * 1024];   // h tile [16 b][512] bf16, swizzled
    __shared__ __align__(16) unsigned char Xl[16 * 1024];   // x tile for t+1, same layout

    const int tid  = threadIdx.x;
    const int bid  = blockIdx.x;
    const int g    = bid >> 4;
    const int s    = bid & 15;
    const int wave = tid >> 6;
    const int lane = tid & 63;
    const int q    = lane >> 4;
    const int bl   = lane & 15;

    // ---- resident fused weights: 16 rows x 1024 K = 32 x short8 = 128 VGPRs ----
    // atomic 8B loads: LLVM will not rematerialize/sink these into the loop.
    const unsigned short* wrow = Wcat + (size_t)(s * 128 + wave * 16 + bl) * KF + q * 8;
    short8 Uh[16], Ux[16];
    #pragma unroll
    for (int kt = 0; kt < 16; ++kt) {
        union { unsigned long long u[2]; short8 v; } wh, wx;
        const unsigned long long* ph = (const unsigned long long*)(wrow + kt * 32);
        const unsigned long long* px = (const unsigned long long*)(wrow + 512 + kt * 32);
        wh.u[0] = __hip_atomic_load(ph,     __ATOMIC_RELAXED, __HIP_MEMORY_SCOPE_AGENT);
        wh.u[1] = __hip_atomic_load(ph + 1, __ATOMIC_RELAXED, __HIP_MEMORY_SCOPE_AGENT);
        wx.u[0] = __hip_atomic_load(px,     __ATOMIC_RELAXED, __HIP_MEMORY_SCOPE_AGENT);
        wx.u[1] = __hip_atomic_load(px + 1, __ATOMIC_RELAXED, __HIP_MEMORY_SCOPE_AGENT);
        Uh[kt] = wh.v;
        Ux[kt] = wx.v;
    }

    // ---- per-lane gate identity: ocol og, batch g*16+bl ----
    const int og = s * 32 + wave * 4 + q;
    const float bi0 = bi[og],           bf0 = bi[og] + bUf[og];
    const float bc0 = bc[og] + bUc[og], bo0 = bo[og] + bUo[og];
    float cst = 0.f;

    // ---- staging identity: thread (sb=batch row, seg=16-col chunk) ----
    const int sb  = tid >> 5;
    const int seg = tid & 31;
    unsigned int* pollp = hflag + (size_t)(g * NSLC + (seg >> 1)) * 16;
    unsigned int* myfl  = hflag + (size_t)(g * NSLC + s) * 16;
    const unsigned short* xst = Xb + (size_t)(g * GB + sb) * T_ * D_ + seg * 16;

    // ---- MFMA-read constants ----
    const unsigned short* xbl = Xb + (size_t)(g * GB + bl) * T_ * D_ + q * 8;

    float* Hout = out;
    float* Cout = out + (size_t)B_ * T_ * D_;

    // ---- prologue: x-partial for t=0 (direct global reads, resident Ux) ----
    f32x4 xa0 = {0.f, 0.f, 0.f, 0.f}, xa1 = {0.f, 0.f, 0.f, 0.f};
    #pragma unroll
    for (int kt = 0; kt < 16; kt += 2) {
        short8 b0 = *(const short8*)(xbl + kt * 32);
        short8 b1 = *(const short8*)(xbl + (kt + 1) * 32);
        xa0 = __builtin_amdgcn_mfma_f32_16x16x32_bf16(Ux[kt],     b0, xa0, 0, 0, 0);
        xa1 = __builtin_amdgcn_mfma_f32_16x16x32_bf16(Ux[kt + 1], b1, xa1, 0, 0, 0);
    }

    for (int t = 0; t < T_; ++t) {
        // ---- x prefetch for t+1 (overlaps poll + h load) ----
        uint4 xr0, xr1;
        const bool hasNext = (t + 1 < T_);
        if (hasNext) {
            const uint4* xs = (const uint4*)(xst + (size_t)(t + 1) * D_);
            xr0 = xs[0]; xr1 = xs[1];
        }

        f32x4 ha0 = {0.f, 0.f, 0.f, 0.f}, ha1 = {0.f, 0.f, 0.f, 0.f};
        if (t > 0) {
            // ---- a) poll own producer's flag (relaxed, LLC-served) ----
            while (__hip_atomic_load(pollp, __ATOMIC_RELAXED, __HIP_MEMORY_SCOPE_AGENT) < (unsigned)t) { }
            asm volatile("" ::: "memory");
            // ---- stage h_{t-1}: 32 B/thread -> swizzled LDS ----
            const unsigned long long* hs = (const unsigned long long*)
                (hbuf + ((size_t)((t + 1) & 1) * B_ + g * GB + sb) * D_ + seg * 16);
            unsigned long long d0 = __hip_atomic_load(hs + 0, __ATOMIC_RELAXED, __HIP_MEMORY_SCOPE_AGENT);
            unsigned long long d1 = __hip_atomic_load(hs + 1, __ATOMIC_RELAXED, __HIP_MEMORY_SCOPE_AGENT);
            unsigned long long d2 = __hip_atomic_load(hs + 2, __ATOMIC_RELAXED, __HIP_MEMORY_SCOPE_AGENT);
            unsigned long long d3 = __hip_atomic_load(hs + 3, __ATOMIC_RELAXED, __HIP_MEMORY_SCOPE_AGENT);
            *(uint4*)(&Hl[loff(sb, seg * 32)]) =
                make_uint4((unsigned)d0, (unsigned)(d0 >> 32), (unsigned)d1, (unsigned)(d1 >> 32));
            *(uint4*)(&Hl[loff(sb, seg * 32 + 16)]) =
                make_uint4((unsigned)d2, (unsigned)(d2 >> 32), (unsigned)d3, (unsigned)(d3 >> 32));
        }

        // ---- b1 (raw): LDS visibility only — no vmcnt drain of prefetch/outputs ----
        asm volatile("s_waitcnt lgkmcnt(0)" ::: "memory");
        __builtin_amdgcn_s_barrier();

        // ---- b) h-MFMAs from LDS, 2 chains ----
        if (t > 0) {
            #pragma unroll
            for (int kt = 0; kt < 16; kt += 2) {
                short8 a0 = *(const short8*)(&Hl[loff(bl, q * 16 + kt * 64)]);
                short8 a1 = *(const short8*)(&Hl[loff(bl, q * 16 + (kt + 1) * 64)]);
                ha0 = __builtin_amdgcn_mfma_f32_16x16x32_bf16(Uh[kt],     a0, ha0, 0, 0, 0);
                ha1 = __builtin_amdgcn_mfma_f32_16x16x32_bf16(Uh[kt + 1], a1, ha1, 0, 0, 0);
            }
        }

        // ---- c) publish x-tile for t+1 into LDS (ordered by barrier2) ----
        if (hasNext) {
            *(uint4*)(&Xl[loff(sb, seg * 32)])      = xr0;
            *(uint4*)(&Xl[loff(sb, seg * 32 + 16)]) = xr1;
        }

        // ---- d) gates (all in-register; D-frag = 4 gates of (og, bl)) ----
        f32x4 A = (ha0 + ha1) + (xa0 + xa1);
        float iv = sigmf(A[0] + bi0);
        float fv = sigmf(A[1] + bf0);
        float cc = tanh_f(A[2] + bc0);
        float ov = sigmf(A[3] + bo0);
        float cv = fv * cst + iv * cc;
        float hv = ov * tanh_f(cv);
        cst = cv;

        // ---- e) publish h (bf16 scatter), barrier2 drains stores, flag ----
        __hip_atomic_store(hbuf + ((size_t)(t & 1) * B_ + g * GB + bl) * D_ + og,
                           f2bf(hv), __ATOMIC_RELAXED, __HIP_MEMORY_SCOPE_AGENT);
        __syncthreads();   // b2: drains h stores (vmcnt 0), orders Xl
        if (tid == 0)
            __hip_atomic_store(myfl, (unsigned)(t + 1), __ATOMIC_RELAXED, __HIP_MEMORY_SCOPE_AGENT);

        // ---- f) x-partial for t+1 from LDS (off critical path) ----
        if (hasNext) {
            f32x4 n0 = {0.f, 0.f, 0.f, 0.f}, n1 = {0.f, 0.f, 0.f, 0.f};
            #pragma unroll
            for (int kt = 0; kt < 16; kt += 2) {
                short8 b0 = *(const short8*)(&Xl[loff(bl, q * 16 + kt * 64)]);
                short8 b1 = *(const short8*)(&Xl[loff(bl, q * 16 + (kt + 1) * 64)]);
                n0 = __builtin_amdgcn_mfma_f32_16x16x32_bf16(Ux[kt],     b0, n0, 0, 0, 0);
                n1 = __builtin_amdgcn_mfma_f32_16x16x32_bf16(Ux[kt + 1], b1, n1, 0, 0, 0);
            }
            xa0 = n0; xa1 = n1;
        }

        // ---- g) streaming outputs (plain stores; WG covers full 128-B lines) ----
        const size_t oi = ((size_t)(g * GB + bl) * T_ + t) * D_ + og;
        Hout[oi] = hv;
        Cout[oi] = cv;
    }
}

extern "C" void kernel_launch(void* const* d_in, const int* in_sizes, int n_in,
                              void* d_out, int out_size, void* d_ws, size_t ws_size,
                              hipStream_t stream) {
    const float* X   = (const float*)d_in[0];
    const float* Wi  = (const float*)d_in[1];
    const float* bi  = (const float*)d_in[2];
    // d_in[3] = Wf, d_in[4] = bf : unused by reference semantics
    const float* Wc  = (const float*)d_in[5];
    const float* bc  = (const float*)d_in[6];
    const float* Wo  = (const float*)d_in[7];
    const float* bo  = (const float*)d_in[8];
    const float* Ui  = (const float*)d_in[9];
    const float* Uf  = (const float*)d_in[10];
    const float* bUf = (const float*)d_in[11];
    const float* Uc  = (const float*)d_in[12];
    const float* bUc = (const float*)d_in[13];
    const float* Uo  = (const float*)d_in[14];
    const float* bUo = (const float*)d_in[15];

    char* ws = (char*)d_ws;
    const size_t XB_BYTES   = (size_t)B_ * T_ * D_ * 2;     // 33,554,432
    const size_t WCAT_BYTES = (size_t)2048 * 1024 * 2;      //  4,194,304
    const size_t HBUF_BYTES = (size_t)2 * B_ * D_ * 2;      //    131,072 (bf16)
    const size_t FLAG_BYTES = (size_t)NGRP * NSLC * 16 * 4; //      4,096

    unsigned short* Xb    = (unsigned short*)ws;
    unsigned short* Wcat  = (unsigned short*)(ws + XB_BYTES);
    unsigned short* hbuf  = (unsigned short*)(ws + XB_BYTES + WCAT_BYTES);
    unsigned int*   hflag = (unsigned int*)(ws + XB_BYTES + WCAT_BYTES + HBUF_BYTES);

    // zero h and the per-producer flags, every call
    hipMemsetAsync(hbuf, 0, HBUF_BYTES + FLAG_BYTES, stream);

    prep_x<<<2048, 256, 0, stream>>>(X, Xb, B_ * T_ * D_ / 4);
    prep_w<<<8192, 256, 0, stream>>>(Wi, Wc, Wo, Ui, Uf, Uc, Uo, Wcat);
    lstm_rec<<<NGRP * NSLC, 512, 0, stream>>>(Xb, Wcat, hbuf, hflag, (float*)d_out,
                                              bi, bc, bo, bUf, bUc, bUo);
}

// Round 11
// 1464.163 us; speedup vs baseline: 2.5956x; 1.0045x over previous
//
#include <hip/hip_runtime.h>

#define B_    64
#define T_    512
#define D_    512
#define KF    1024      // fused weight K = [h(512) ; x(512)]
#define NGRP  4         // batch groups
#define NSLC  16        // WG slices per group
#define GB    16        // batches per group

using short8 = __attribute__((ext_vector_type(8))) short;
using f32x4  = __attribute__((ext_vector_type(4))) float;

__device__ __forceinline__ unsigned short f2bf(float f) {
    unsigned int u = __float_as_uint(f);
    u = (u + 0x7fffu + ((u >> 16) & 1u)) >> 16;
    return (unsigned short)u;
}
__device__ __forceinline__ float sigmf(float x)  { return 1.0f / (1.0f + __expf(-x)); }
__device__ __forceinline__ float tanh_f(float x) { return 1.0f - 2.0f / (1.0f + __expf(2.0f * x)); }

// LDS tile [16 rows][1024 B]; XOR spreads stride-32B staging writes (~4-way)
// and row-major MFMA reads across banks. Bijective per row. (Proven R8/R10.)
__device__ __forceinline__ int loff(int row, int kb) {
    return row * 1024 + (kb ^ ((((row & 7) ^ ((kb >> 7) & 7)) << 4)));
}

// ---- prep: X fp32 -> bf16 ----
__global__ void prep_x(const float* __restrict__ X, unsigned short* __restrict__ Xb, int n4) {
    int stride = gridDim.x * blockDim.x;
    for (int i = blockIdx.x * blockDim.x + threadIdx.x; i < n4; i += stride) {
        float4 v = ((const float4*)X)[i];
        ushort4 o;
        o.x = f2bf(v.x); o.y = f2bf(v.y); o.z = f2bf(v.z); o.w = f2bf(v.w);
        ((ushort4*)Xb)[i] = o;
    }
}

// ---- prep: fused weight Wcat[r = o*4+g][k]; gate g: 0=i(Ui,Wi) 1=f(Uf,Wi quirk) 2=c(Uc,Wc) 3=o(Uo,Wo)
__global__ void prep_w(const float* __restrict__ Wi, const float* __restrict__ Wc,
                       const float* __restrict__ Wo,
                       const float* __restrict__ Ui, const float* __restrict__ Uf,
                       const float* __restrict__ Uc, const float* __restrict__ Uo,
                       unsigned short* __restrict__ Wcat) {
    int idx = blockIdx.x * blockDim.x + threadIdx.x;
    if (idx >= 2048 * 1024) return;
    int r = idx >> 10, k = idx & 1023;
    int o = r >> 2, g = r & 3;
    const float* U = (g == 0) ? Ui : (g == 1) ? Uf : (g == 2) ? Uc : Uo;
    const float* W = (g < 2) ? Wi : (g == 2) ? Wc : Wo;
    float v = (k < 512) ? U[o * 512 + k] : W[o * 512 + (k - 512)];
    Wcat[idx] = f2bf(v);
}

// ---- persistent recurrence, 64 WGs (1/CU, 8 waves = EXACTLY 2/SIMD) ----
// R10 baseline. Single delta: tid0 polls the 16 padded producer flags and
// broadcasts via LDS `go` (kills the 512-thread poll storm at the LLC).
__attribute__((amdgpu_waves_per_eu(2, 2)))
__launch_bounds__(512)
__global__ void lstm_rec(const unsigned short* __restrict__ Xb,
                         const unsigned short* __restrict__ Wcat,
                         unsigned short* __restrict__ hbuf,   // [2][64][512] bf16
                         unsigned int* __restrict__ hflag,    // [NGRP*NSLC] padded x16 dwords
                         float* __restrict__ out,             // H then C (fp32)
                         const float* __restrict__ bi, const float* __restrict__ bc,
                         const float* __restrict__ bo, const float* __restrict__ bUf,
                         const float* __restrict__ bUc, const float* __restrict__ bUo) {
    __shared__ __align__(16) unsigned char Hl[16 * 1024];   // h tile [16 b][512] bf16, swizzled
    __shared__ __align__(16) unsigned char Xl[16 * 1024];   // x tile for t+1, same layout
    __shared__ int go;

    const int tid  = threadIdx.x;
    const int bid  = blockIdx.x;
    const int g    = bid >> 4;
    const int s    = bid & 15;
    const int wave = tid >> 6;
    const int lane = tid & 63;
    const int q    = lane >> 4;
    const int bl   = lane & 15;

    if (tid == 0) go = 0;   // visible to all before first spin (t=1) via t=0's barriers

    // ---- resident fused weights: 16 rows x 1024 K = 32 x short8 = 128 VGPRs ----
    // atomic 8B loads: LLVM will not rematerialize/sink these into the loop.
    const unsigned short* wrow = Wcat + (size_t)(s * 128 + wave * 16 + bl) * KF + q * 8;
    short8 Uh[16], Ux[16];
    #pragma unroll
    for (int kt = 0; kt < 16; ++kt) {
        union { unsigned long long u[2]; short8 v; } wh, wx;
        const unsigned long long* ph = (const unsigned long long*)(wrow + kt * 32);
        const unsigned long long* px = (const unsigned long long*)(wrow + 512 + kt * 32);
        wh.u[0] = __hip_atomic_load(ph,     __ATOMIC_RELAXED, __HIP_MEMORY_SCOPE_AGENT);
        wh.u[1] = __hip_atomic_load(ph + 1, __ATOMIC_RELAXED, __HIP_MEMORY_SCOPE_AGENT);
        wx.u[0] = __hip_atomic_load(px,     __ATOMIC_RELAXED, __HIP_MEMORY_SCOPE_AGENT);
        wx.u[1] = __hip_atomic_load(px + 1, __ATOMIC_RELAXED, __HIP_MEMORY_SCOPE_AGENT);
        Uh[kt] = wh.v;
        Ux[kt] = wx.v;
    }

    // ---- per-lane gate identity: ocol og, batch g*16+bl ----
    const int og = s * 32 + wave * 4 + q;
    const float bi0 = bi[og],           bf0 = bi[og] + bUf[og];
    const float bc0 = bc[og] + bUc[og], bo0 = bo[og] + bUo[og];
    float cst = 0.f;

    // ---- staging identity: thread (sb=batch row, seg=16-col chunk) ----
    const int sb  = tid >> 5;
    const int seg = tid & 31;
    unsigned int* gfl  = hflag + (size_t)g * NSLC * 16;   // group's 16 padded flag lines
    unsigned int* myfl = hflag + (size_t)(g * NSLC + s) * 16;
    const unsigned short* xst = Xb + (size_t)(g * GB + sb) * T_ * D_ + seg * 16;

    // ---- MFMA-read constants ----
    const unsigned short* xbl = Xb + (size_t)(g * GB + bl) * T_ * D_ + q * 8;

    float* Hout = out;
    float* Cout = out + (size_t)B_ * T_ * D_;

    // ---- prologue: x-partial for t=0 (direct global reads, resident Ux) ----
    f32x4 xa0 = {0.f, 0.f, 0.f, 0.f}, xa1 = {0.f, 0.f, 0.f, 0.f};
    #pragma unroll
    for (int kt = 0; kt < 16; kt += 2) {
        short8 b0 = *(const short8*)(xbl + kt * 32);
        short8 b1 = *(const short8*)(xbl + (kt + 1) * 32);
        xa0 = __builtin_amdgcn_mfma_f32_16x16x32_bf16(Ux[kt],     b0, xa0, 0, 0, 0);
        xa1 = __builtin_amdgcn_mfma_f32_16x16x32_bf16(Ux[kt + 1], b1, xa1, 0, 0, 0);
    }

    for (int t = 0; t < T_; ++t) {
        // ---- x prefetch for t+1 (overlaps poll + h load) ----
        uint4 xr0, xr1;
        const bool hasNext = (t + 1 < T_);
        if (hasNext) {
            const uint4* xs = (const uint4*)(xst + (size_t)(t + 1) * D_);
            xr0 = xs[0]; xr1 = xs[1];
        }

        f32x4 ha0 = {0.f, 0.f, 0.f, 0.f}, ha1 = {0.f, 0.f, 0.f, 0.f};
        if (t > 0) {
            // ---- a) detection: tid0 polls all 16 producer flags; LDS broadcast ----
            if (tid == 0) {
                const unsigned want = (unsigned)t;
                for (;;) {
                    bool ok = true;
                    #pragma unroll
                    for (int j = 0; j < 16; ++j)
                        ok &= (__hip_atomic_load(gfl + j * 16, __ATOMIC_RELAXED,
                                                 __HIP_MEMORY_SCOPE_AGENT) >= want);
                    if (ok) break;
                }
                __hip_atomic_store(&go, t, __ATOMIC_RELAXED, __HIP_MEMORY_SCOPE_WORKGROUP);
            } else if (lane == 0) {
                while (__hip_atomic_load(&go, __ATOMIC_RELAXED, __HIP_MEMORY_SCOPE_WORKGROUP) < t) { }
            }
            asm volatile("" ::: "memory");

            // ---- stage h_{t-1}: 32 B/thread -> swizzled LDS ----
            const unsigned long long* hs = (const unsigned long long*)
                (hbuf + ((size_t)((t + 1) & 1) * B_ + g * GB + sb) * D_ + seg * 16);
            unsigned long long d0 = __hip_atomic_load(hs + 0, __ATOMIC_RELAXED, __HIP_MEMORY_SCOPE_AGENT);
            unsigned long long d1 = __hip_atomic_load(hs + 1, __ATOMIC_RELAXED, __HIP_MEMORY_SCOPE_AGENT);
            unsigned long long d2 = __hip_atomic_load(hs + 2, __ATOMIC_RELAXED, __HIP_MEMORY_SCOPE_AGENT);
            unsigned long long d3 = __hip_atomic_load(hs + 3, __ATOMIC_RELAXED, __HIP_MEMORY_SCOPE_AGENT);
            *(uint4*)(&Hl[loff(sb, seg * 32)]) =
                make_uint4((unsigned)d0, (unsigned)(d0 >> 32), (unsigned)d1, (unsigned)(d1 >> 32));
            *(uint4*)(&Hl[loff(sb, seg * 32 + 16)]) =
                make_uint4((unsigned)d2, (unsigned)(d2 >> 32), (unsigned)d3, (unsigned)(d3 >> 32));
        }

        // ---- b1 (raw): LDS visibility only — no vmcnt drain of prefetch/outputs ----
        asm volatile("s_waitcnt lgkmcnt(0)" ::: "memory");
        __builtin_amdgcn_s_barrier();

        // ---- b) h-MFMAs from LDS, 2 chains ----
        if (t > 0) {
            #pragma unroll
            for (int kt = 0; kt < 16; kt += 2) {
                short8 a0 = *(const short8*)(&Hl[loff(bl, q * 16 + kt * 64)]);
                short8 a1 = *(const short8*)(&Hl[loff(bl, q * 16 + (kt + 1) * 64)]);
                ha0 = __builtin_amdgcn_mfma_f32_16x16x32_bf16(Uh[kt],     a0, ha0, 0, 0, 0);
                ha1 = __builtin_amdgcn_mfma_f32_16x16x32_bf16(Uh[kt + 1], a1, ha1, 0, 0, 0);
            }
        }

        // ---- c) publish x-tile for t+1 into LDS (ordered by barrier2) ----
        if (hasNext) {
            *(uint4*)(&Xl[loff(sb, seg * 32)])      = xr0;
            *(uint4*)(&Xl[loff(sb, seg * 32 + 16)]) = xr1;
        }

        // ---- d) gates (all in-register; D-frag = 4 gates of (og, bl)) ----
        f32x4 A = (ha0 + ha1) + (xa0 + xa1);
        float iv = sigmf(A[0] + bi0);
        float fv = sigmf(A[1] + bf0);
        float cc = tanh_f(A[2] + bc0);
        float ov = sigmf(A[3] + bo0);
        float cv = fv * cst + iv * cc;
        float hv = ov * tanh_f(cv);
        cst = cv;

        // ---- e) publish h (bf16 scatter), barrier2 drains stores, flag ----
        __hip_atomic_store(hbuf + ((size_t)(t & 1) * B_ + g * GB + bl) * D_ + og,
                           f2bf(hv), __ATOMIC_RELAXED, __HIP_MEMORY_SCOPE_AGENT);
        __syncthreads();   // b2: drains h stores (vmcnt 0), orders Xl
        if (tid == 0)
            __hip_atomic_store(myfl, (unsigned)(t + 1), __ATOMIC_RELAXED, __HIP_MEMORY_SCOPE_AGENT);

        // ---- f) x-partial for t+1 from LDS (fills the flag-propagation window) ----
        if (hasNext) {
            f32x4 n0 = {0.f, 0.f, 0.f, 0.f}, n1 = {0.f, 0.f, 0.f, 0.f};
            #pragma unroll
            for (int kt = 0; kt < 16; kt += 2) {
                short8 b0 = *(const short8*)(&Xl[loff(bl, q * 16 + kt * 64)]);
                short8 b1 = *(const short8*)(&Xl[loff(bl, q * 16 + (kt + 1) * 64)]);
                n0 = __builtin_amdgcn_mfma_f32_16x16x32_bf16(Ux[kt],     b0, n0, 0, 0, 0);
                n1 = __builtin_amdgcn_mfma_f32_16x16x32_bf16(Ux[kt + 1], b1, n1, 0, 0, 0);
            }
            xa0 = n0; xa1 = n1;
        }

        // ---- g) streaming outputs (plain stores; WG covers full 128-B lines) ----
        const size_t oi = ((size_t)(g * GB + bl) * T_ + t) * D_ + og;
        Hout[oi] = hv;
        Cout[oi] = cv;
    }
}

extern "C" void kernel_launch(void* const* d_in, const int* in_sizes, int n_in,
                              void* d_out, int out_size, void* d_ws, size_t ws_size,
                              hipStream_t stream) {
    const float* X   = (const float*)d_in[0];
    const float* Wi  = (const float*)d_in[1];
    const float* bi  = (const float*)d_in[2];
    // d_in[3] = Wf, d_in[4] = bf : unused by reference semantics
    const float* Wc  = (const float*)d_in[5];
    const float* bc  = (const float*)d_in[6];
    const float* Wo  = (const float*)d_in[7];
    const float* bo  = (const float*)d_in[8];
    const float* Ui  = (const float*)d_in[9];
    const float* Uf  = (const float*)d_in[10];
    const float* bUf = (const float*)d_in[11];
    const float* Uc  = (const float*)d_in[12];
    const float* bUc = (const float*)d_in[13];
    const float* Uo  = (const float*)d_in[14];
    const float* bUo = (const float*)d_in[15];

    char* ws = (char*)d_ws;
    const size_t XB_BYTES   = (size_t)B_ * T_ * D_ * 2;     // 33,554,432
    const size_t WCAT_BYTES = (size_t)2048 * 1024 * 2;      //  4,194,304
    const size_t HBUF_BYTES = (size_t)2 * B_ * D_ * 2;      //    131,072 (bf16)
    const size_t FLAG_BYTES = (size_t)NGRP * NSLC * 16 * 4; //      4,096

    unsigned short* Xb    = (unsigned short*)ws;
    unsigned short* Wcat  = (unsigned short*)(ws + XB_BYTES);
    unsigned short* hbuf  = (unsigned short*)(ws + XB_BYTES + WCAT_BYTES);
    unsigned int*   hflag = (unsigned int*)(ws + XB_BYTES + WCAT_BYTES + HBUF_BYTES);

    // zero h and the per-producer flags, every call
    hipMemsetAsync(hbuf, 0, HBUF_BYTES + FLAG_BYTES, stream);

    prep_x<<<2048, 256, 0, stream>>>(X, Xb, B_ * T_ * D_ / 4);
    prep_w<<<8192, 256, 0, stream>>>(Wi, Wc, Wo, Ui, Uf, Uc, Uo, Wcat);
    lstm_rec<<<NGRP * NSLC, 512, 0, stream>>>(Xb, Wcat, hbuf, hflag, (float*)d_out,
                                              bi, bc, bo, bUf, bUc, bUo);
}